// Round 16
// baseline (144.379 us; speedup 1.0000x reference)
//
#include <hip/hip_runtime.h>

#define BATCH 2
#define SEQ 2048
#define DMODEL 768
#define NH 12
#define DHEAD 64
#define D3 (3 * DMODEL)  // 2304

typedef float f32x4 __attribute__((ext_vector_type(4)));
typedef __bf16 bf16x8 __attribute__((ext_vector_type(8)));
typedef __bf16 bf16x4 __attribute__((ext_vector_type(4)));

#define NEG_INF (-__builtin_inff())
#define SCL 0.18033688011112042f  // (1/sqrt(64)) * log2(e), folded into W_q/b_q

__device__ __forceinline__ void g2l16(const void* g, void* l) {
    __builtin_amdgcn_global_load_lds(
        (const __attribute__((address_space(1))) void*)g,
        (__attribute__((address_space(3))) void*)l,
        16, 0, 0);
}

__device__ __forceinline__ unsigned pack_bf16(float lo, float hi) {
    unsigned a = __builtin_bit_cast(unsigned short, (__bf16)lo);
    unsigned b = __builtin_bit_cast(unsigned short, (__bf16)hi);
    return a | (b << 16);
}

// ---------------- fused f32 -> bf16 convert (counts in float4 units) ----------------
#define XQ 786432   // 2*2048*768 / 4
#define WQQ 442368  // 2304*768 / 4
#define WOQ 147456  // 768*768 / 4
#define WQROWS 147456  // float4 idx bound for w_qkv rows < 768
__global__ __launch_bounds__(256) void cvt3_kernel(const float* __restrict__ X,
                                                   const float* __restrict__ Wq,
                                                   const float* __restrict__ Wo,
                                                   __bf16* __restrict__ Xb,
                                                   __bf16* __restrict__ Wqb,
                                                   __bf16* __restrict__ Wob) {
    int i = blockIdx.x * 256 + threadIdx.x;
    const float* s; __bf16* d; int k;
    float scl = 1.0f;
    if (i < XQ)            { s = X;  d = Xb;  k = i; }
    else if (i < XQ + WQQ) { s = Wq; d = Wqb; k = i - XQ; if (k < WQROWS) scl = SCL; }
    else                   { s = Wo; d = Wob; k = i - XQ - WQQ; }
    float4 v = ((const float4*)s)[k];
    bf16x4 o;
    o[0] = (__bf16)(v.x * scl); o[1] = (__bf16)(v.y * scl);
    o[2] = (__bf16)(v.z * scl); o[3] = (__bf16)(v.w * scl);
    ((bf16x4*)d)[k] = o;
}

// ---------------- padding mask -> lengths; also emit scaled b_qkv copy ----------------
__global__ __launch_bounds__(256) void lens_kernel(const unsigned char* __restrict__ mask,
                                                   const float* __restrict__ bq,
                                                   float* __restrict__ bqs,
                                                   int* __restrict__ lens) {
    __shared__ int nz_s;
    __shared__ int cnt[2];
    if (threadIdx.x == 0) { nz_s = 0; cnt[0] = 0; cnt[1] = 0; }
    __syncthreads();
    for (int i = threadIdx.x; i < D3; i += 256)
        bqs[i] = bq[i] * (i < DMODEL ? SCL : 1.0f);
    uint4 mv = ((const uint4*)mask)[threadIdx.x];  // covers bytes [0,4096)
    if (mv.x | mv.y | mv.z | mv.w) nz_s = 1;
    __syncthreads();
    int c0 = 0, c1 = 0;
    if (nz_s) {  // bool layout
        for (int s = threadIdx.x; s < SEQ; s += 256) {
            c0 += (mask[s] != 0);
            c1 += (mask[SEQ + s] != 0);
        }
    } else {     // int32 layout
        const int* mi = (const int*)mask;
        for (int s = threadIdx.x; s < SEQ; s += 256) {
            c0 += (mi[s] != 0);
            c1 += (mi[SEQ + s] != 0);
        }
    }
    atomicAdd(&cnt[0], c0);
    atomicAdd(&cnt[1], c1);
    __syncthreads();
    if (threadIdx.x == 0) {
        lens[0] = SEQ - cnt[0];
        lens[1] = SEQ - cnt[1];
    }
}

// -------- QKV GEMM: split outputs: Qd natural, Kd per-head dense, Vp tiled-transposed --
__global__ __launch_bounds__(256) void gemm_qkv(const __bf16* __restrict__ A,
                                                const __bf16* __restrict__ Bw,
                                                const float* __restrict__ bias,
                                                __bf16* __restrict__ Qd,
                                                __bf16* __restrict__ Kd,
                                                __bf16* __restrict__ Vp) {
    const int K = 768;
    __shared__ __align__(16) __bf16 As[128][64];
    __shared__ __align__(16) __bf16 Bs[128][64];
    const int tid = threadIdx.x;
    const int wave = tid >> 6, lane = tid & 63;
    const int bm = blockIdx.x * 128, bn = blockIdx.y * 128;
    const int wr = (wave >> 1) * 64, wc = (wave & 1) * 64;
    const int l15 = lane & 15, lg = lane >> 4;
    const int rsub = lane >> 3;
    const int csub = (((lane & 7) ^ rsub) * 8);
    const int rswz = (l15 & 7) * 8;

    f32x4 acc[4][4] = {};

    for (int kt = 0; kt < K; kt += 64) {
#pragma unroll
        for (int it = 0; it < 4; ++it) {
            int c = it * 4 + wave;
            int row = c * 8 + rsub;
            g2l16(A + (size_t)(bm + row) * K + kt + csub, &As[0][0] + c * 512);
            g2l16(Bw + (size_t)(bn + row) * K + kt + csub, &Bs[0][0] + c * 512);
        }
        __syncthreads();
#pragma unroll
        for (int kk = 0; kk < 2; ++kk) {
            bf16x8 af[4], bfr[4];
            const int col = (kk * 32 + lg * 8) ^ rswz;
#pragma unroll
            for (int m = 0; m < 4; ++m)
                af[m] = *(const bf16x8*)(&As[0][0] + (wr + m * 16 + l15) * 64 + col);
#pragma unroll
            for (int n = 0; n < 4; ++n)
                bfr[n] = *(const bf16x8*)(&Bs[0][0] + (wc + n * 16 + l15) * 64 + col);
#pragma unroll
            for (int m = 0; m < 4; ++m)
#pragma unroll
                for (int n = 0; n < 4; ++n)
                    acc[m][n] = __builtin_amdgcn_mfma_f32_16x16x32_bf16(af[m], bfr[n], acc[m][n], 0, 0, 0);
        }
        __syncthreads();
    }

#pragma unroll
    for (int n = 0; n < 4; ++n) {
        int col = bn + wc + n * 16 + l15;
        float bv = bias[col];
#pragma unroll
        for (int m = 0; m < 4; ++m) {
#pragma unroll
            for (int j = 0; j < 4; ++j) {
                int row = bm + wr + m * 16 + lg * 4 + j;
                __bf16 v = (__bf16)(acc[m][n][j] + bv);
                if (bn < 768) {
                    Qd[(size_t)row * 768 + col] = v;
                } else if (bn < 1536) {
                    int kc = col - 768;
                    int hh = kc >> 6, dh = kc & 63;
                    int bb = row >> 11, key = row & 2047;
                    Kd[(size_t)(bb * NH + hh) * 131072 + key * 64 + dh] = v;
                } else {
                    int vc = col - 1536;
                    int hh = vc >> 6, dh = vc & 63;
                    int bb = row >> 11, key = row & 2047;
                    Vp[(size_t)(bb * NH + hh) * 131072 + (key >> 6) * 4096 + dh * 64 + (key & 63)] = v;
                }
            }
        }
    }
}

// ---------------- out-projection GEMM (validated round 3) ----------------
__global__ __launch_bounds__(256) void gemm_out(const __bf16* __restrict__ A,
                                                const __bf16* __restrict__ Bw,
                                                const float* __restrict__ bias,
                                                float* __restrict__ Cout,
                                                int M, int N, int K) {
    __shared__ __align__(16) __bf16 As[128][64];
    __shared__ __align__(16) __bf16 Bs[128][64];
    const int tid = threadIdx.x;
    const int wave = tid >> 6, lane = tid & 63;
    const int bm = blockIdx.x * 128, bn = blockIdx.y * 128;
    const int wr = (wave >> 1) * 64, wc = (wave & 1) * 64;
    const int l15 = lane & 15, lg = lane >> 4;
    const int rsub = lane >> 3;
    const int csub = (((lane & 7) ^ rsub) * 8);
    const int rswz = (l15 & 7) * 8;

    f32x4 acc[4][4] = {};

    for (int kt = 0; kt < K; kt += 64) {
#pragma unroll
        for (int it = 0; it < 4; ++it) {
            int c = it * 4 + wave;
            int row = c * 8 + rsub;
            g2l16(A + (size_t)(bm + row) * K + kt + csub, &As[0][0] + c * 512);
            g2l16(Bw + (size_t)(bn + row) * K + kt + csub, &Bs[0][0] + c * 512);
        }
        __syncthreads();
#pragma unroll
        for (int kk = 0; kk < 2; ++kk) {
            bf16x8 af[4], bfr[4];
            const int col = (kk * 32 + lg * 8) ^ rswz;
#pragma unroll
            for (int m = 0; m < 4; ++m)
                af[m] = *(const bf16x8*)(&As[0][0] + (wr + m * 16 + l15) * 64 + col);
#pragma unroll
            for (int n = 0; n < 4; ++n)
                bfr[n] = *(const bf16x8*)(&Bs[0][0] + (wc + n * 16 + l15) * 64 + col);
#pragma unroll
            for (int m = 0; m < 4; ++m)
#pragma unroll
                for (int n = 0; n < 4; ++n)
                    acc[m][n] = __builtin_amdgcn_mfma_f32_16x16x32_bf16(af[m], bfr[n], acc[m][n], 0, 0, 0);
        }
        __syncthreads();
    }

#pragma unroll
    for (int n = 0; n < 4; ++n) {
        int col = bn + wc + n * 16 + l15;
        float bv = bias[col];
#pragma unroll
        for (int m = 0; m < 4; ++m) {
#pragma unroll
            for (int j = 0; j < 4; ++j) {
                int row = bm + wr + m * 16 + lg * 4 + j;
                Cout[(size_t)row * N + col] = acc[m][n][j] + bv;
            }
        }
    }
}

// ------- flash attention: block-cooperative LDS staging, 4 waves x 32 q-rows ----------
// Block covers 128 q-rows of one (b,h); K/V tiles staged ONCE per block into
// double-buffered LDS via g2l16 (linear memcpy from dense Kd / pre-transposed Vp),
// XOR-swizzled on the GLOBAL SOURCE (linear LDS dest, rule #21): byte ^=
// ((row^(row>>3))&7)<<4, applied identically on fragment ds_reads -> bank-balanced.
// One barrier per tile; prefetch(t+1) issued before compute(t) so the implicit
// vmcnt(0)-before-barrier drain is latency-covered. Shuffle-free P->PV (permuted K
// rows), folded scale, static-max softmax, per-lane l partials. All 384 blocks
// co-resident (32KB LDS); XCD-pinned heads, heavy q-blocks first.
__global__ __launch_bounds__(256) void attn_kernel(const __bf16* __restrict__ Qd,
                                                   const __bf16* __restrict__ Kd,
                                                   const int* __restrict__ lens,
                                                   const __bf16* __restrict__ Vp,
                                                   __bf16* __restrict__ Out) {
    __shared__ __align__(16) __bf16 KT[2][4096];  // 2 x 8KB K tiles (swizzled cols)
    __shared__ __align__(16) __bf16 VT[2][4096];  // 2 x 8KB V^T tiles (swizzled cols)

    const int lane = threadIdx.x & 63, wave = threadIdx.x >> 6;
    const int l15 = lane & 15, lg = lane >> 4;
    const int blk = blockIdx.x;
    const int xcd = blk & 7, idx = blk >> 3;   // idx 0..47
    const int hl = idx % 3, qbd = idx / 3;     // qbd 0..15
    const int qb = 15 - qbd;                   // heavy first
    const int bh = xcd * 3 + hl;
    const int b = bh / NH, h = bh % NH;
    const int len = lens[b];
    const int q0b = qb * 128;
    const int q0 = q0b + wave * 32;            // this wave's 32 rows

    const __bf16* Ktile0 = Kd + (size_t)bh * 131072;
    const __bf16* Vtile0 = Vp + (size_t)bh * 131072;

    // staging decode: lane (lr,lc); chunk c: row r=c*8+lr, src col-granule lc^((lr^c)&7)
    const int lr = lane >> 3, lc = lane & 7;

    // Q fragments (B-operand) for both 16-row subtiles
    bf16x8 qf[2][2];
    int qcap[2];
#pragma unroll
    for (int m = 0; m < 2; ++m) {
        const __bf16* qp_ = Qd + (size_t)(b * SEQ + q0 + m * 16 + l15) * DMODEL + h * DHEAD + lg * 8;
        qf[m][0] = *(const bf16x8*)qp_;
        qf[m][1] = *(const bf16x8*)(qp_ + 32);
        int myq = q0 + m * 16 + l15;
        qcap[m] = (len - 1 < myq) ? (len - 1) : myq;
    }

    int kmax = q0b + 128;
    if (len < kmax) kmax = len;
    const int nt = (kmax + 63) >> 6;           // block tile count
    int mymax = q0 + 32;
    if (len < mymax) mymax = len;
    const int mynt = (mymax + 63) >> 6;        // this wave's active tiles

    // fragment read byte-offsets (within an 8KB tile), swizzle folded in
    const int prow = ((l15 >> 2) << 3) + (l15 & 3);
    int koff[2][4], voff[2][4];
#pragma unroll
    for (int n = 0; n < 4; ++n) {
        int tr = ((n >> 1) << 5) + ((n & 1) << 2) + prow;
        int sw = ((tr ^ (tr >> 3)) & 7) << 4;
#pragma unroll
        for (int kk = 0; kk < 2; ++kk)
            koff[kk][n] = tr * 128 + ((kk * 64 + lg * 16) ^ sw);
        int tv = n * 16 + l15;
        int sv = ((tv ^ (tv >> 3)) & 7) << 4;
#pragma unroll
        for (int kk = 0; kk < 2; ++kk)
            voff[kk][n] = tv * 128 + ((kk * 64 + lg * 16) ^ sv);
    }

    f32x4 accO[2][4] = {};
    float l_part[2] = {0.f, 0.f};

    auto stage = [&](int buf, int t) {
#pragma unroll
        for (int i = 0; i < 2; ++i) {
            int c = wave * 2 + i;              // chunk 0..7 (1KB each)
            int r = c * 8 + lr;
            int srcoff = r * 64 + 8 * (lc ^ ((lr ^ c) & 7));  // inverse-swizzled source
            g2l16(Ktile0 + t * 4096 + srcoff, &KT[buf][0] + c * 512);
            g2l16(Vtile0 + t * 4096 + srcoff, &VT[buf][0] + c * 512);
        }
    };

    auto compute = [&](int buf, int t) {
        const int k0 = t * 64;
        const char* kb = (const char*)&KT[buf][0];
        const char* vb = (const char*)&VT[buf][0];

        bf16x8 kf[2][4];
#pragma unroll
        for (int kk = 0; kk < 2; ++kk)
#pragma unroll
            for (int n = 0; n < 4; ++n)
                kf[kk][n] = *(const bf16x8*)(kb + koff[kk][n]);

        // S^T = K Q^T (permuted rows), log2 domain
        f32x4 sc[2][4];
        __builtin_amdgcn_s_setprio(1);
#pragma unroll
        for (int m = 0; m < 2; ++m)
#pragma unroll
            for (int n = 0; n < 4; ++n) {
                sc[m][n] = __builtin_amdgcn_mfma_f32_16x16x32_bf16(kf[0][n], qf[m][0],
                                                                   f32x4{0.f, 0.f, 0.f, 0.f}, 0, 0, 0);
                sc[m][n] = __builtin_amdgcn_mfma_f32_16x16x32_bf16(kf[1][n], qf[m][1], sc[m][n], 0, 0, 0);
            }
        __builtin_amdgcn_s_setprio(0);

        bf16x8 vf[2][4];
#pragma unroll
        for (int kk = 0; kk < 2; ++kk)
#pragma unroll
            for (int n = 0; n < 4; ++n)
                vf[kk][n] = *(const bf16x8*)(vb + voff[kk][n]);

        bf16x8 pa[2][2];
#pragma unroll
        for (int m = 0; m < 2; ++m) {
            const bool full = (k0 + 63 <= q0 + m * 16) && (k0 + 63 < len);
            float psum = 0.f;
            unsigned pk[4][2];
#pragma unroll
            for (int n = 0; n < 4; ++n) {
                const int keyb = k0 + ((n >> 1) << 5) + lg * 8 + ((n & 1) << 2);
                float pv[4];
#pragma unroll
                for (int j = 0; j < 4; ++j) {
                    float e = exp2f(sc[m][n][j]);
                    if (!full) e = (keyb + j <= qcap[m]) ? e : 0.f;
                    pv[j] = e;
                }
                psum += (pv[0] + pv[1]) + (pv[2] + pv[3]);
                pk[n][0] = pack_bf16(pv[0], pv[1]);
                pk[n][1] = pack_bf16(pv[2], pv[3]);
            }
            l_part[m] += psum;

            uint4 u0 = {pk[0][0], pk[0][1], pk[1][0], pk[1][1]};
            uint4 u1 = {pk[2][0], pk[2][1], pk[3][0], pk[3][1]};
            pa[m][0] = __builtin_bit_cast(bf16x8, u0);
            pa[m][1] = __builtin_bit_cast(bf16x8, u1);
        }

        __builtin_amdgcn_s_setprio(1);
#pragma unroll
        for (int m = 0; m < 2; ++m)
#pragma unroll
            for (int kk = 0; kk < 2; ++kk)
#pragma unroll
                for (int n = 0; n < 4; ++n)
                    accO[m][n] = __builtin_amdgcn_mfma_f32_16x16x32_bf16(pa[m][kk], vf[kk][n], accO[m][n], 0, 0, 0);
        __builtin_amdgcn_s_setprio(0);
    };

    // prologue: stage tile 0; drain; then 1 barrier per tile
    stage(0, 0);
    __syncthreads();
    for (int t = 0; t < nt; ++t) {
        const int cur = t & 1;
        if (t + 1 < nt) stage(cur ^ 1, t + 1);  // async prefetch (covered by compute)
        if (t < mynt) compute(cur, t);          // wave-uniform causal skip
        __syncthreads();                        // drains prefetch; guards buffer reuse
    }

    // epilogue: reduce l across the 4 lane-groups, normalize, store
#pragma unroll
    for (int m = 0; m < 2; ++m) {
        float lp = l_part[m];
        lp += __shfl_xor(lp, 16);
        lp += __shfl_xor(lp, 32);
        float inv = 1.0f / lp;
        float inv_j[4];
#pragma unroll
        for (int j = 0; j < 4; ++j) inv_j[j] = __shfl(inv, lg * 4 + j);
#pragma unroll
        for (int n = 0; n < 4; ++n)
#pragma unroll
            for (int j = 0; j < 4; ++j) {
                int q = q0 + m * 16 + lg * 4 + j;
                Out[(size_t)(b * SEQ + q) * DMODEL + h * DHEAD + n * 16 + l15] =
                    (__bf16)(accO[m][n][j] * inv_j[j]);
            }
    }
}

extern "C" void kernel_launch(void* const* d_in, const int* in_sizes, int n_in,
                              void* d_out, int out_size, void* d_ws, size_t ws_size,
                              hipStream_t stream) {
    const float* query = (const float*)d_in[0];
    const unsigned char* mask = (const unsigned char*)d_in[1];
    const float* w_qkv = (const float*)d_in[2];
    const float* b_qkv = (const float*)d_in[3];
    const float* w_out = (const float*)d_in[4];
    const float* b_out = (const float*)d_in[5];
    float* out = (float*)d_out;

    if (ws_size < 36200448ull) return;
    char* p = (char*)d_ws;
    int* lens = (int*)p;        p += 256;
    float* bqs = (float*)p;     p += 2304 * 4 + 256;
    __bf16* Xb = (__bf16*)p;    p += (size_t)4096 * 768 * 2;
    __bf16* Wqb = (__bf16*)p;   p += (size_t)2304 * 768 * 2;
    __bf16* Wob = (__bf16*)p;   p += (size_t)768 * 768 * 2;
    __bf16* Qd = (__bf16*)p;    p += (size_t)4096 * 768 * 2;
    __bf16* Kd = (__bf16*)p;    p += (size_t)4096 * 768 * 2;
    __bf16* Vp = (__bf16*)p;    p += (size_t)4096 * 768 * 2;
    __bf16* AOb = (__bf16*)p;   p += (size_t)4096 * 768 * 2;

    lens_kernel<<<1, 256, 0, stream>>>(mask, b_qkv, bqs, lens);
    cvt3_kernel<<<(XQ + WQQ + WOQ) / 256, 256, 0, stream>>>(query, w_qkv, w_out, Xb, Wqb, Wob);

    // QKV projection with split outputs (Q pre-scaled; K dense per-head; V tiled-transposed)
    gemm_qkv<<<dim3(32, 18), 256, 0, stream>>>(Xb, Wqb, bqs, Qd, Kd, Vp);
    // attention: 384 co-resident blocks, 4 waves each, LDS-cooperative staging
    attn_kernel<<<384, 256, 0, stream>>>(Qd, Kd, lens, Vp, AOb);
    // output projection: [4096,768] @ [768,768]^T -> f32 d_out
    gemm_out<<<dim3(32, 6), 256, 0, stream>>>(AOb, Wob, b_out, out, 4096, 768, 768);
}

// Round 17
// 135.223 us; speedup vs baseline: 1.0677x; 1.0677x over previous
//
#include <hip/hip_runtime.h>

#define BATCH 2
#define SEQ 2048
#define DMODEL 768
#define NH 12
#define DHEAD 64
#define D3 (3 * DMODEL)  // 2304

typedef float f32x4 __attribute__((ext_vector_type(4)));
typedef __bf16 bf16x8 __attribute__((ext_vector_type(8)));
typedef __bf16 bf16x4 __attribute__((ext_vector_type(4)));

#define NEG_INF (-__builtin_inff())
#define SCL 0.18033688011112042f  // (1/sqrt(64)) * log2(e), folded into W_q/b_q

__device__ __forceinline__ void g2l16(const void* g, void* l) {
    __builtin_amdgcn_global_load_lds(
        (const __attribute__((address_space(1))) void*)g,
        (__attribute__((address_space(3))) void*)l,
        16, 0, 0);
}

// one-instruction packed f32x2 -> bf16x2 (lo -> low16, hi -> high16)
__device__ __forceinline__ unsigned cvtpk(float lo, float hi) {
    unsigned r;
    asm("v_cvt_pk_bf16_f32 %0, %1, %2" : "=v"(r) : "v"(lo), "v"(hi));
    return r;
}

// ---------------- fused f32 -> bf16 convert (counts in float4 units) ----------------
#define XQ 786432   // 2*2048*768 / 4
#define WQQ 442368  // 2304*768 / 4
#define WOQ 147456  // 768*768 / 4
#define WQROWS 147456  // float4 idx bound for w_qkv rows < 768
__global__ __launch_bounds__(256) void cvt3_kernel(const float* __restrict__ X,
                                                   const float* __restrict__ Wq,
                                                   const float* __restrict__ Wo,
                                                   __bf16* __restrict__ Xb,
                                                   __bf16* __restrict__ Wqb,
                                                   __bf16* __restrict__ Wob) {
    int i = blockIdx.x * 256 + threadIdx.x;
    const float* s; __bf16* d; int k;
    float scl = 1.0f;
    if (i < XQ)            { s = X;  d = Xb;  k = i; }
    else if (i < XQ + WQQ) { s = Wq; d = Wqb; k = i - XQ; if (k < WQROWS) scl = SCL; }
    else                   { s = Wo; d = Wob; k = i - XQ - WQQ; }
    float4 v = ((const float4*)s)[k];
    bf16x4 o;
    o[0] = (__bf16)(v.x * scl); o[1] = (__bf16)(v.y * scl);
    o[2] = (__bf16)(v.z * scl); o[3] = (__bf16)(v.w * scl);
    ((bf16x4*)d)[k] = o;
}

// ---------------- padding mask -> lengths; also emit scaled b_qkv copy ----------------
__global__ __launch_bounds__(256) void lens_kernel(const unsigned char* __restrict__ mask,
                                                   const float* __restrict__ bq,
                                                   float* __restrict__ bqs,
                                                   int* __restrict__ lens) {
    __shared__ int nz_s;
    __shared__ int cnt[2];
    if (threadIdx.x == 0) { nz_s = 0; cnt[0] = 0; cnt[1] = 0; }
    __syncthreads();
    for (int i = threadIdx.x; i < D3; i += 256)
        bqs[i] = bq[i] * (i < DMODEL ? SCL : 1.0f);
    uint4 mv = ((const uint4*)mask)[threadIdx.x];  // covers bytes [0,4096)
    if (mv.x | mv.y | mv.z | mv.w) nz_s = 1;
    __syncthreads();
    int c0 = 0, c1 = 0;
    if (nz_s) {  // bool layout
        for (int s = threadIdx.x; s < SEQ; s += 256) {
            c0 += (mask[s] != 0);
            c1 += (mask[SEQ + s] != 0);
        }
    } else {     // int32 layout
        const int* mi = (const int*)mask;
        for (int s = threadIdx.x; s < SEQ; s += 256) {
            c0 += (mi[s] != 0);
            c1 += (mi[SEQ + s] != 0);
        }
    }
    atomicAdd(&cnt[0], c0);
    atomicAdd(&cnt[1], c1);
    __syncthreads();
    if (threadIdx.x == 0) {
        lens[0] = SEQ - cnt[0];
        lens[1] = SEQ - cnt[1];
    }
}

// -------- QKV GEMM: split outputs: Qd natural, Kd per-head dense, Vp tiled-transposed --
__global__ __launch_bounds__(256) void gemm_qkv(const __bf16* __restrict__ A,
                                                const __bf16* __restrict__ Bw,
                                                const float* __restrict__ bias,
                                                __bf16* __restrict__ Qd,
                                                __bf16* __restrict__ Kd,
                                                __bf16* __restrict__ Vp) {
    const int K = 768;
    __shared__ __align__(16) __bf16 As[128][64];
    __shared__ __align__(16) __bf16 Bs[128][64];
    const int tid = threadIdx.x;
    const int wave = tid >> 6, lane = tid & 63;
    const int bm = blockIdx.x * 128, bn = blockIdx.y * 128;
    const int wr = (wave >> 1) * 64, wc = (wave & 1) * 64;
    const int l15 = lane & 15, lg = lane >> 4;
    const int rsub = lane >> 3;
    const int csub = (((lane & 7) ^ rsub) * 8);
    const int rswz = (l15 & 7) * 8;

    f32x4 acc[4][4] = {};

    for (int kt = 0; kt < K; kt += 64) {
#pragma unroll
        for (int it = 0; it < 4; ++it) {
            int c = it * 4 + wave;
            int row = c * 8 + rsub;
            g2l16(A + (size_t)(bm + row) * K + kt + csub, &As[0][0] + c * 512);
            g2l16(Bw + (size_t)(bn + row) * K + kt + csub, &Bs[0][0] + c * 512);
        }
        __syncthreads();
#pragma unroll
        for (int kk = 0; kk < 2; ++kk) {
            bf16x8 af[4], bfr[4];
            const int col = (kk * 32 + lg * 8) ^ rswz;
#pragma unroll
            for (int m = 0; m < 4; ++m)
                af[m] = *(const bf16x8*)(&As[0][0] + (wr + m * 16 + l15) * 64 + col);
#pragma unroll
            for (int n = 0; n < 4; ++n)
                bfr[n] = *(const bf16x8*)(&Bs[0][0] + (wc + n * 16 + l15) * 64 + col);
#pragma unroll
            for (int m = 0; m < 4; ++m)
#pragma unroll
                for (int n = 0; n < 4; ++n)
                    acc[m][n] = __builtin_amdgcn_mfma_f32_16x16x32_bf16(af[m], bfr[n], acc[m][n], 0, 0, 0);
        }
        __syncthreads();
    }

#pragma unroll
    for (int n = 0; n < 4; ++n) {
        int col = bn + wc + n * 16 + l15;
        float bv = bias[col];
#pragma unroll
        for (int m = 0; m < 4; ++m) {
#pragma unroll
            for (int j = 0; j < 4; ++j) {
                int row = bm + wr + m * 16 + lg * 4 + j;
                __bf16 v = (__bf16)(acc[m][n][j] + bv);
                if (bn < 768) {
                    Qd[(size_t)row * 768 + col] = v;
                } else if (bn < 1536) {
                    int kc = col - 768;
                    int hh = kc >> 6, dh = kc & 63;
                    int bb = row >> 11, key = row & 2047;
                    Kd[(size_t)(bb * NH + hh) * 131072 + key * 64 + dh] = v;
                } else {
                    int vc = col - 1536;
                    int hh = vc >> 6, dh = vc & 63;
                    int bb = row >> 11, key = row & 2047;
                    Vp[(size_t)(bb * NH + hh) * 131072 + (key >> 6) * 4096 + dh * 64 + (key & 63)] = v;
                }
            }
        }
    }
}

// ---------------- out-projection GEMM (validated round 3) ----------------
__global__ __launch_bounds__(256) void gemm_out(const __bf16* __restrict__ A,
                                                const __bf16* __restrict__ Bw,
                                                const float* __restrict__ bias,
                                                float* __restrict__ Cout,
                                                int M, int N, int K) {
    __shared__ __align__(16) __bf16 As[128][64];
    __shared__ __align__(16) __bf16 Bs[128][64];
    const int tid = threadIdx.x;
    const int wave = tid >> 6, lane = tid & 63;
    const int bm = blockIdx.x * 128, bn = blockIdx.y * 128;
    const int wr = (wave >> 1) * 64, wc = (wave & 1) * 64;
    const int l15 = lane & 15, lg = lane >> 4;
    const int rsub = lane >> 3;
    const int csub = (((lane & 7) ^ rsub) * 8);
    const int rswz = (l15 & 7) * 8;

    f32x4 acc[4][4] = {};

    for (int kt = 0; kt < K; kt += 64) {
#pragma unroll
        for (int it = 0; it < 4; ++it) {
            int c = it * 4 + wave;
            int row = c * 8 + rsub;
            g2l16(A + (size_t)(bm + row) * K + kt + csub, &As[0][0] + c * 512);
            g2l16(Bw + (size_t)(bn + row) * K + kt + csub, &Bs[0][0] + c * 512);
        }
        __syncthreads();
#pragma unroll
        for (int kk = 0; kk < 2; ++kk) {
            bf16x8 af[4], bfr[4];
            const int col = (kk * 32 + lg * 8) ^ rswz;
#pragma unroll
            for (int m = 0; m < 4; ++m)
                af[m] = *(const bf16x8*)(&As[0][0] + (wr + m * 16 + l15) * 64 + col);
#pragma unroll
            for (int n = 0; n < 4; ++n)
                bfr[n] = *(const bf16x8*)(&Bs[0][0] + (wc + n * 16 + l15) * 64 + col);
#pragma unroll
            for (int m = 0; m < 4; ++m)
#pragma unroll
                for (int n = 0; n < 4; ++n)
                    acc[m][n] = __builtin_amdgcn_mfma_f32_16x16x32_bf16(af[m], bfr[n], acc[m][n], 0, 0, 0);
        }
        __syncthreads();
    }

#pragma unroll
    for (int n = 0; n < 4; ++n) {
        int col = bn + wc + n * 16 + l15;
        float bv = bias[col];
#pragma unroll
        for (int m = 0; m < 4; ++m) {
#pragma unroll
            for (int j = 0; j < 4; ++j) {
                int row = bm + wr + m * 16 + lg * 4 + j;
                Cout[(size_t)row * N + col] = acc[m][n][j] + bv;
            }
        }
    }
}

// ------- flash attention: r15 pipeline + cvt_pk softmax pack + l-sum via MFMA ---------
// Iteration t: V-load(t) -> QK(t+1) -> K-load(t+2) -> softmax(t) -> PV(t). No vmcnt(0)
// in steady state (V oldest outstanding; K prefetch survives the PV wait). Softmax pack
// uses v_cvt_pk_bf16_f32 (1 inst/pair vs ~7 VALU bf16-round sequence). Row-sum l is
// computed by an extra PV MFMA against an all-ones B-fragment (accL[j] = sum_k P,
// per-row, replicated across lanes) - deletes the psum adds, l_part, and all epilogue
// cross-lane shuffles. Shuffle-free P->PV (permuted K rows), folded scale, static-max
// softmax, dense Kd / tiled Vp layouts, XCD-pinned heads, heavy-first.
__global__ __launch_bounds__(128) void attn_kernel(const __bf16* __restrict__ Qd,
                                                   const __bf16* __restrict__ Kd,
                                                   const int* __restrict__ lens,
                                                   const __bf16* __restrict__ Vp,
                                                   __bf16* __restrict__ Out) {
    const int lane = threadIdx.x & 63, wave = threadIdx.x >> 6;
    const int l15 = lane & 15, lg = lane >> 4;
    const int blk = blockIdx.x;
    const int xcd = blk & 7, idx = blk >> 3;   // idx 0..95
    const int hl = idx % 3, pd2 = idx / 3;     // pd2 0..31
    const int p = 63 - (pd2 * 2 + wave);       // heavy first; waves share bh
    const int bh = xcd * 3 + hl;
    const int b = bh / NH, h = bh % NH;
    const int len = lens[b];
    const int q0 = p * 32;

    // permuted K row for this lane: prow = (l15>>2)*8 + (l15&3)
    const int prow = ((l15 >> 2) << 3) + (l15 & 3);
    const __bf16* kbase = Kd + (size_t)bh * 131072 + prow * 64 + lg * 8;
    const __bf16* vbase = Vp + (size_t)bh * 131072 + l15 * 64 + lg * 8;

    // Q fragments (B-operand) for both subtiles
    bf16x8 qf[2][2];
    int qcap[2];
#pragma unroll
    for (int m = 0; m < 2; ++m) {
        const __bf16* qp_ = Qd + (size_t)(b * SEQ + q0 + m * 16 + l15) * DMODEL + h * DHEAD + lg * 8;
        qf[m][0] = *(const bf16x8*)qp_;
        qf[m][1] = *(const bf16x8*)(qp_ + 32);
        int myq = q0 + m * 16 + l15;
        qcap[m] = (len - 1 < myq) ? (len - 1) : myq;
    }

    int kmax = q0 + 32;
    if (len < kmax) kmax = len;
    const int nt = (kmax + 63) >> 6;

    // all-ones bf16 B-fragment for the l-sum MFMA
    const uint4 onesu = {0x3F803F80u, 0x3F803F80u, 0x3F803F80u, 0x3F803F80u};
    const bf16x8 ones = __builtin_bit_cast(bf16x8, onesu);

    f32x4 accO[2][4] = {};
    f32x4 accL[2] = {};            // accL[m][j] = running row-sum of P for row lg*4+j

    bf16x8 kA[2][4], kB[2][4];     // double-buffered K fragments
    bf16x8 vfA[2][4], vfB[2][4];   // double-buffered V fragments
    f32x4 scA[2][4], scB[2][4];    // double-buffered score tiles

    auto kload = [&](bf16x8(&kf)[2][4], int kt) {
        const int k0 = kt * 64;
#pragma unroll
        for (int n = 0; n < 4; ++n) {
            const int roff = (k0 + ((n >> 1) << 5) + ((n & 1) << 2)) * 64;
#pragma unroll
            for (int kkd = 0; kkd < 2; ++kkd)
                kf[kkd][n] = *(const bf16x8*)(kbase + roff + kkd * 32);
        }
    };

    auto vload = [&](bf16x8(&vf)[2][4], int kt) {
        const __bf16* vt = vbase + kt * 4096;
#pragma unroll
        for (int kk = 0; kk < 2; ++kk)
#pragma unroll
            for (int n = 0; n < 4; ++n)
                vf[kk][n] = *(const bf16x8*)(vt + n * 1024 + kk * 32);
    };

    auto qk = [&](f32x4(&sc)[2][4], bf16x8(&kf)[2][4]) {
        __builtin_amdgcn_s_setprio(1);
#pragma unroll
        for (int m = 0; m < 2; ++m)
#pragma unroll
            for (int n = 0; n < 4; ++n) {
                sc[m][n] = __builtin_amdgcn_mfma_f32_16x16x32_bf16(kf[0][n], qf[m][0],
                                                                   f32x4{0.f, 0.f, 0.f, 0.f}, 0, 0, 0);
                sc[m][n] = __builtin_amdgcn_mfma_f32_16x16x32_bf16(kf[1][n], qf[m][1], sc[m][n], 0, 0, 0);
            }
        __builtin_amdgcn_s_setprio(0);
    };

    auto step = [&](f32x4(&sc)[2][4], bf16x8(&vf)[2][4], int kt) {
        const int k0 = kt * 64;
        bf16x8 pa[2][2];
#pragma unroll
        for (int m = 0; m < 2; ++m) {
            const bool full = (k0 + 63 <= q0 + m * 16) && (k0 + 63 < len);
            unsigned pk[4][2];
#pragma unroll
            for (int n = 0; n < 4; ++n) {
                const int keyb = k0 + ((n >> 1) << 5) + lg * 8 + ((n & 1) << 2);
                float pv[4];
#pragma unroll
                for (int j = 0; j < 4; ++j) {
                    float e = exp2f(sc[m][n][j]);
                    if (!full) e = (keyb + j <= qcap[m]) ? e : 0.f;
                    pv[j] = e;
                }
                pk[n][0] = cvtpk(pv[0], pv[1]);
                pk[n][1] = cvtpk(pv[2], pv[3]);
            }
            uint4 u0 = {pk[0][0], pk[0][1], pk[1][0], pk[1][1]};
            uint4 u1 = {pk[2][0], pk[2][1], pk[3][0], pk[3][1]};
            pa[m][0] = __builtin_bit_cast(bf16x8, u0);
            pa[m][1] = __builtin_bit_cast(bf16x8, u1);
        }

        __builtin_amdgcn_s_setprio(1);
#pragma unroll
        for (int m = 0; m < 2; ++m) {
#pragma unroll
            for (int kk = 0; kk < 2; ++kk) {
#pragma unroll
                for (int n = 0; n < 4; ++n)
                    accO[m][n] = __builtin_amdgcn_mfma_f32_16x16x32_bf16(pa[m][kk], vf[kk][n], accO[m][n], 0, 0, 0);
                accL[m] = __builtin_amdgcn_mfma_f32_16x16x32_bf16(pa[m][kk], ones, accL[m], 0, 0, 0);
            }
        }
        __builtin_amdgcn_s_setprio(0);
    };

    // pipeline prologue: S(0) from kA; K(1) -> kB
    kload(kA, 0);
    qk(scA, kA);
    if (nt > 1) kload(kB, 1);

    int t = 0;
    for (;;) {
        {   // scores in scA; next K in kB; kA free; V -> vfA
            const bool hasN = (t + 1 < nt);
            vload(vfA, t);                     // V FIRST (oldest outstanding)
            if (hasN) qk(scB, kB);             // waits only on old K buffer
            if (t + 2 < nt) kload(kA, t + 2);  // prefetch; stays in flight thru PV
            step(scA, vfA, t);                 // softmax covers V; PV partial wait
            ++t;
            if (!hasN) break;
        }
        {   // scores in scB; next K in kA; kB free; V -> vfB
            const bool hasN = (t + 1 < nt);
            vload(vfB, t);
            if (hasN) qk(scA, kA);
            if (t + 2 < nt) kload(kB, t + 2);
            step(scB, vfB, t);
            ++t;
            if (!hasN) break;
        }
    }

    // epilogue: accL[m][j] already holds per-row l at every lane; no shuffles
#pragma unroll
    for (int m = 0; m < 2; ++m) {
        float inv_j[4];
#pragma unroll
        for (int j = 0; j < 4; ++j) inv_j[j] = 1.0f / accL[m][j];
#pragma unroll
        for (int n = 0; n < 4; ++n)
#pragma unroll
            for (int j = 0; j < 4; ++j) {
                int q = q0 + m * 16 + lg * 4 + j;
                Out[(size_t)(b * SEQ + q) * DMODEL + h * DHEAD + n * 16 + l15] =
                    (__bf16)(accO[m][n][j] * inv_j[j]);
            }
    }
}

extern "C" void kernel_launch(void* const* d_in, const int* in_sizes, int n_in,
                              void* d_out, int out_size, void* d_ws, size_t ws_size,
                              hipStream_t stream) {
    const float* query = (const float*)d_in[0];
    const unsigned char* mask = (const unsigned char*)d_in[1];
    const float* w_qkv = (const float*)d_in[2];
    const float* b_qkv = (const float*)d_in[3];
    const float* w_out = (const float*)d_in[4];
    const float* b_out = (const float*)d_in[5];
    float* out = (float*)d_out;

    if (ws_size < 36200448ull) return;
    char* p = (char*)d_ws;
    int* lens = (int*)p;        p += 256;
    float* bqs = (float*)p;     p += 2304 * 4 + 256;
    __bf16* Xb = (__bf16*)p;    p += (size_t)4096 * 768 * 2;
    __bf16* Wqb = (__bf16*)p;   p += (size_t)2304 * 768 * 2;
    __bf16* Wob = (__bf16*)p;   p += (size_t)768 * 768 * 2;
    __bf16* Qd = (__bf16*)p;    p += (size_t)4096 * 768 * 2;
    __bf16* Kd = (__bf16*)p;    p += (size_t)4096 * 768 * 2;
    __bf16* Vp = (__bf16*)p;    p += (size_t)4096 * 768 * 2;
    __bf16* AOb = (__bf16*)p;   p += (size_t)4096 * 768 * 2;

    lens_kernel<<<1, 256, 0, stream>>>(mask, b_qkv, bqs, lens);
    cvt3_kernel<<<(XQ + WQQ + WOQ) / 256, 256, 0, stream>>>(query, w_qkv, w_out, Xb, Wqb, Wob);

    // QKV projection with split outputs (Q pre-scaled; K dense per-head; V tiled-transposed)
    gemm_qkv<<<dim3(32, 18), 256, 0, stream>>>(Xb, Wqb, bqs, Qd, Kd, Vp);
    // attention: 768 blocks x 2 pipelined waves
    attn_kernel<<<768, 128, 0, stream>>>(Qd, Kd, lens, Vp, AOb);
    // output projection: [4096,768] @ [768,768]^T -> f32 d_out
    gemm_out<<<dim3(32, 6), 256, 0, stream>>>(AOb, Wob, b_out, out, 4096, 768, 768);
}

// Round 18
// 129.183 us; speedup vs baseline: 1.1176x; 1.0468x over previous
//
#include <hip/hip_runtime.h>

#define BATCH 2
#define SEQ 2048
#define DMODEL 768
#define NH 12
#define DHEAD 64
#define D3 (3 * DMODEL)  // 2304

typedef float f32x4 __attribute__((ext_vector_type(4)));
typedef __bf16 bf16x8 __attribute__((ext_vector_type(8)));
typedef __bf16 bf16x4 __attribute__((ext_vector_type(4)));

#define NEG_INF (-__builtin_inff())
#define SCL 0.18033688011112042f  // (1/sqrt(64)) * log2(e), folded into W_q/b_q

__device__ __forceinline__ void g2l16(const void* g, void* l) {
    __builtin_amdgcn_global_load_lds(
        (const __attribute__((address_space(1))) void*)g,
        (__attribute__((address_space(3))) void*)l,
        16, 0, 0);
}

// one-instruction packed f32x2 -> bf16x2 (lo -> low16, hi -> high16)
__device__ __forceinline__ unsigned cvtpk(float lo, float hi) {
    unsigned r;
    asm("v_cvt_pk_bf16_f32 %0, %1, %2" : "=v"(r) : "v"(lo), "v"(hi));
    return r;
}

// -------- fused prep: f32->bf16 convert for X/Wq/Wo + lens/bqs (last block) ----------
#define XQ 786432   // 2*2048*768 / 4
#define WQQ 442368  // 2304*768 / 4
#define WOQ 147456  // 768*768 / 4
#define WQROWS 147456  // float4 idx bound for w_qkv rows < 768
#define CVTBLKS 5376   // (XQ+WQQ+WOQ)/256
__global__ __launch_bounds__(256) void prep_kernel(const float* __restrict__ X,
                                                   const float* __restrict__ Wq,
                                                   const float* __restrict__ Wo,
                                                   __bf16* __restrict__ Xb,
                                                   __bf16* __restrict__ Wqb,
                                                   __bf16* __restrict__ Wob,
                                                   const unsigned char* __restrict__ mask,
                                                   const float* __restrict__ bq,
                                                   float* __restrict__ bqs,
                                                   int* __restrict__ lens) {
    if (blockIdx.x == CVTBLKS) {
        // lens + scaled-bias block
        __shared__ int nz_s;
        __shared__ int cnt[2];
        if (threadIdx.x == 0) { nz_s = 0; cnt[0] = 0; cnt[1] = 0; }
        __syncthreads();
        for (int i = threadIdx.x; i < D3; i += 256)
            bqs[i] = bq[i] * (i < DMODEL ? SCL : 1.0f);
        uint4 mv = ((const uint4*)mask)[threadIdx.x];  // covers bytes [0,4096)
        if (mv.x | mv.y | mv.z | mv.w) nz_s = 1;
        __syncthreads();
        int c0 = 0, c1 = 0;
        if (nz_s) {  // bool layout
            for (int s = threadIdx.x; s < SEQ; s += 256) {
                c0 += (mask[s] != 0);
                c1 += (mask[SEQ + s] != 0);
            }
        } else {     // int32 layout
            const int* mi = (const int*)mask;
            for (int s = threadIdx.x; s < SEQ; s += 256) {
                c0 += (mi[s] != 0);
                c1 += (mi[SEQ + s] != 0);
            }
        }
        atomicAdd(&cnt[0], c0);
        atomicAdd(&cnt[1], c1);
        __syncthreads();
        if (threadIdx.x == 0) {
            lens[0] = SEQ - cnt[0];
            lens[1] = SEQ - cnt[1];
        }
        return;
    }
    int i = blockIdx.x * 256 + threadIdx.x;
    const float* s; __bf16* d; int k;
    float scl = 1.0f;
    if (i < XQ)            { s = X;  d = Xb;  k = i; }
    else if (i < XQ + WQQ) { s = Wq; d = Wqb; k = i - XQ; if (k < WQROWS) scl = SCL; }
    else                   { s = Wo; d = Wob; k = i - XQ - WQQ; }
    float4 v = ((const float4*)s)[k];
    bf16x4 o;
    o[0] = (__bf16)(v.x * scl); o[1] = (__bf16)(v.y * scl);
    o[2] = (__bf16)(v.z * scl); o[3] = (__bf16)(v.w * scl);
    ((bf16x4*)d)[k] = o;
}

// -------- QKV GEMM: split outputs: Qd natural, Kd per-head dense, Vp tiled-transposed --
__global__ __launch_bounds__(256) void gemm_qkv(const __bf16* __restrict__ A,
                                                const __bf16* __restrict__ Bw,
                                                const float* __restrict__ bias,
                                                __bf16* __restrict__ Qd,
                                                __bf16* __restrict__ Kd,
                                                __bf16* __restrict__ Vp) {
    const int K = 768;
    __shared__ __align__(16) __bf16 As[128][64];
    __shared__ __align__(16) __bf16 Bs[128][64];
    const int tid = threadIdx.x;
    const int wave = tid >> 6, lane = tid & 63;
    const int bm = blockIdx.x * 128, bn = blockIdx.y * 128;
    const int wr = (wave >> 1) * 64, wc = (wave & 1) * 64;
    const int l15 = lane & 15, lg = lane >> 4;
    const int rsub = lane >> 3;
    const int csub = (((lane & 7) ^ rsub) * 8);
    const int rswz = (l15 & 7) * 8;

    f32x4 acc[4][4] = {};

    for (int kt = 0; kt < K; kt += 64) {
#pragma unroll
        for (int it = 0; it < 4; ++it) {
            int c = it * 4 + wave;
            int row = c * 8 + rsub;
            g2l16(A + (size_t)(bm + row) * K + kt + csub, &As[0][0] + c * 512);
            g2l16(Bw + (size_t)(bn + row) * K + kt + csub, &Bs[0][0] + c * 512);
        }
        __syncthreads();
#pragma unroll
        for (int kk = 0; kk < 2; ++kk) {
            bf16x8 af[4], bfr[4];
            const int col = (kk * 32 + lg * 8) ^ rswz;
#pragma unroll
            for (int m = 0; m < 4; ++m)
                af[m] = *(const bf16x8*)(&As[0][0] + (wr + m * 16 + l15) * 64 + col);
#pragma unroll
            for (int n = 0; n < 4; ++n)
                bfr[n] = *(const bf16x8*)(&Bs[0][0] + (wc + n * 16 + l15) * 64 + col);
#pragma unroll
            for (int m = 0; m < 4; ++m)
#pragma unroll
                for (int n = 0; n < 4; ++n)
                    acc[m][n] = __builtin_amdgcn_mfma_f32_16x16x32_bf16(af[m], bfr[n], acc[m][n], 0, 0, 0);
        }
        __syncthreads();
    }

#pragma unroll
    for (int n = 0; n < 4; ++n) {
        int col = bn + wc + n * 16 + l15;
        float bv = bias[col];
#pragma unroll
        for (int m = 0; m < 4; ++m) {
#pragma unroll
            for (int j = 0; j < 4; ++j) {
                int row = bm + wr + m * 16 + lg * 4 + j;
                __bf16 v = (__bf16)(acc[m][n][j] + bv);
                if (bn < 768) {
                    Qd[(size_t)row * 768 + col] = v;
                } else if (bn < 1536) {
                    int kc = col - 768;
                    int hh = kc >> 6, dh = kc & 63;
                    int bb = row >> 11, key = row & 2047;
                    Kd[(size_t)(bb * NH + hh) * 131072 + key * 64 + dh] = v;
                } else {
                    int vc = col - 1536;
                    int hh = vc >> 6, dh = vc & 63;
                    int bb = row >> 11, key = row & 2047;
                    Vp[(size_t)(bb * NH + hh) * 131072 + (key >> 6) * 4096 + dh * 64 + (key & 63)] = v;
                }
            }
        }
    }
}

// ---------------- out-projection GEMM: 64x128 tiles (384 blocks, full CU fill) --------
__global__ __launch_bounds__(256) void gemm_out(const __bf16* __restrict__ A,
                                                const __bf16* __restrict__ Bw,
                                                const float* __restrict__ bias,
                                                float* __restrict__ Cout,
                                                int M, int N, int K) {
    __shared__ __align__(16) __bf16 As[64][64];
    __shared__ __align__(16) __bf16 Bs[128][64];
    const int tid = threadIdx.x;
    const int wave = tid >> 6, lane = tid & 63;
    const int bm = blockIdx.x * 64, bn = blockIdx.y * 128;
    const int wr = (wave >> 1) * 32, wc = (wave & 1) * 64;
    const int l15 = lane & 15, lg = lane >> 4;
    const int rsub = lane >> 3;
    const int csub = (((lane & 7) ^ rsub) * 8);
    const int rswz = (l15 & 7) * 8;

    f32x4 acc[2][4] = {};

    for (int kt = 0; kt < K; kt += 64) {
#pragma unroll
        for (int it = 0; it < 2; ++it) {   // A: 8 chunks (64 rows)
            int c = it * 4 + wave;
            int row = c * 8 + rsub;
            g2l16(A + (size_t)(bm + row) * K + kt + csub, &As[0][0] + c * 512);
        }
#pragma unroll
        for (int it = 0; it < 4; ++it) {   // B: 16 chunks (128 rows)
            int c = it * 4 + wave;
            int row = c * 8 + rsub;
            g2l16(Bw + (size_t)(bn + row) * K + kt + csub, &Bs[0][0] + c * 512);
        }
        __syncthreads();
#pragma unroll
        for (int kk = 0; kk < 2; ++kk) {
            bf16x8 af[2], bfr[4];
            const int col = (kk * 32 + lg * 8) ^ rswz;
#pragma unroll
            for (int m = 0; m < 2; ++m)
                af[m] = *(const bf16x8*)(&As[0][0] + (wr + m * 16 + l15) * 64 + col);
#pragma unroll
            for (int n = 0; n < 4; ++n)
                bfr[n] = *(const bf16x8*)(&Bs[0][0] + (wc + n * 16 + l15) * 64 + col);
#pragma unroll
            for (int m = 0; m < 2; ++m)
#pragma unroll
                for (int n = 0; n < 4; ++n)
                    acc[m][n] = __builtin_amdgcn_mfma_f32_16x16x32_bf16(af[m], bfr[n], acc[m][n], 0, 0, 0);
        }
        __syncthreads();
    }

#pragma unroll
    for (int n = 0; n < 4; ++n) {
        int col = bn + wc + n * 16 + l15;
        float bv = bias[col];
#pragma unroll
        for (int m = 0; m < 2; ++m) {
#pragma unroll
            for (int j = 0; j < 4; ++j) {
                int row = bm + wr + m * 16 + lg * 4 + j;
                Cout[(size_t)row * N + col] = acc[m][n][j] + bv;
            }
        }
    }
}

// ------- flash attention: r17 (frozen) — pipeline + cvt_pk pack + l-sum via MFMA ------
__global__ __launch_bounds__(128) void attn_kernel(const __bf16* __restrict__ Qd,
                                                   const __bf16* __restrict__ Kd,
                                                   const int* __restrict__ lens,
                                                   const __bf16* __restrict__ Vp,
                                                   __bf16* __restrict__ Out) {
    const int lane = threadIdx.x & 63, wave = threadIdx.x >> 6;
    const int l15 = lane & 15, lg = lane >> 4;
    const int blk = blockIdx.x;
    const int xcd = blk & 7, idx = blk >> 3;   // idx 0..95
    const int hl = idx % 3, pd2 = idx / 3;     // pd2 0..31
    const int p = 63 - (pd2 * 2 + wave);       // heavy first; waves share bh
    const int bh = xcd * 3 + hl;
    const int b = bh / NH, h = bh % NH;
    const int len = lens[b];
    const int q0 = p * 32;

    // permuted K row for this lane: prow = (l15>>2)*8 + (l15&3)
    const int prow = ((l15 >> 2) << 3) + (l15 & 3);
    const __bf16* kbase = Kd + (size_t)bh * 131072 + prow * 64 + lg * 8;
    const __bf16* vbase = Vp + (size_t)bh * 131072 + l15 * 64 + lg * 8;

    // Q fragments (B-operand) for both subtiles
    bf16x8 qf[2][2];
    int qcap[2];
#pragma unroll
    for (int m = 0; m < 2; ++m) {
        const __bf16* qp_ = Qd + (size_t)(b * SEQ + q0 + m * 16 + l15) * DMODEL + h * DHEAD + lg * 8;
        qf[m][0] = *(const bf16x8*)qp_;
        qf[m][1] = *(const bf16x8*)(qp_ + 32);
        int myq = q0 + m * 16 + l15;
        qcap[m] = (len - 1 < myq) ? (len - 1) : myq;
    }

    int kmax = q0 + 32;
    if (len < kmax) kmax = len;
    const int nt = (kmax + 63) >> 6;

    // all-ones bf16 B-fragment for the l-sum MFMA
    const uint4 onesu = {0x3F803F80u, 0x3F803F80u, 0x3F803F80u, 0x3F803F80u};
    const bf16x8 ones = __builtin_bit_cast(bf16x8, onesu);

    f32x4 accO[2][4] = {};
    f32x4 accL[2] = {};            // accL[m][j] = running row-sum of P for row lg*4+j

    bf16x8 kA[2][4], kB[2][4];     // double-buffered K fragments
    bf16x8 vfA[2][4], vfB[2][4];   // double-buffered V fragments
    f32x4 scA[2][4], scB[2][4];    // double-buffered score tiles

    auto kload = [&](bf16x8(&kf)[2][4], int kt) {
        const int k0 = kt * 64;
#pragma unroll
        for (int n = 0; n < 4; ++n) {
            const int roff = (k0 + ((n >> 1) << 5) + ((n & 1) << 2)) * 64;
#pragma unroll
            for (int kkd = 0; kkd < 2; ++kkd)
                kf[kkd][n] = *(const bf16x8*)(kbase + roff + kkd * 32);
        }
    };

    auto vload = [&](bf16x8(&vf)[2][4], int kt) {
        const __bf16* vt = vbase + kt * 4096;
#pragma unroll
        for (int kk = 0; kk < 2; ++kk)
#pragma unroll
            for (int n = 0; n < 4; ++n)
                vf[kk][n] = *(const bf16x8*)(vt + n * 1024 + kk * 32);
    };

    auto qk = [&](f32x4(&sc)[2][4], bf16x8(&kf)[2][4]) {
        __builtin_amdgcn_s_setprio(1);
#pragma unroll
        for (int m = 0; m < 2; ++m)
#pragma unroll
            for (int n = 0; n < 4; ++n) {
                sc[m][n] = __builtin_amdgcn_mfma_f32_16x16x32_bf16(kf[0][n], qf[m][0],
                                                                   f32x4{0.f, 0.f, 0.f, 0.f}, 0, 0, 0);
                sc[m][n] = __builtin_amdgcn_mfma_f32_16x16x32_bf16(kf[1][n], qf[m][1], sc[m][n], 0, 0, 0);
            }
        __builtin_amdgcn_s_setprio(0);
    };

    auto step = [&](f32x4(&sc)[2][4], bf16x8(&vf)[2][4], int kt) {
        const int k0 = kt * 64;
        bf16x8 pa[2][2];
#pragma unroll
        for (int m = 0; m < 2; ++m) {
            const bool full = (k0 + 63 <= q0 + m * 16) && (k0 + 63 < len);
            unsigned pk[4][2];
#pragma unroll
            for (int n = 0; n < 4; ++n) {
                const int keyb = k0 + ((n >> 1) << 5) + lg * 8 + ((n & 1) << 2);
                float pv[4];
#pragma unroll
                for (int j = 0; j < 4; ++j) {
                    float e = exp2f(sc[m][n][j]);
                    if (!full) e = (keyb + j <= qcap[m]) ? e : 0.f;
                    pv[j] = e;
                }
                pk[n][0] = cvtpk(pv[0], pv[1]);
                pk[n][1] = cvtpk(pv[2], pv[3]);
            }
            uint4 u0 = {pk[0][0], pk[0][1], pk[1][0], pk[1][1]};
            uint4 u1 = {pk[2][0], pk[2][1], pk[3][0], pk[3][1]};
            pa[m][0] = __builtin_bit_cast(bf16x8, u0);
            pa[m][1] = __builtin_bit_cast(bf16x8, u1);
        }

        __builtin_amdgcn_s_setprio(1);
#pragma unroll
        for (int m = 0; m < 2; ++m) {
#pragma unroll
            for (int kk = 0; kk < 2; ++kk) {
#pragma unroll
                for (int n = 0; n < 4; ++n)
                    accO[m][n] = __builtin_amdgcn_mfma_f32_16x16x32_bf16(pa[m][kk], vf[kk][n], accO[m][n], 0, 0, 0);
                accL[m] = __builtin_amdgcn_mfma_f32_16x16x32_bf16(pa[m][kk], ones, accL[m], 0, 0, 0);
            }
        }
        __builtin_amdgcn_s_setprio(0);
    };

    // pipeline prologue: S(0) from kA; K(1) -> kB
    kload(kA, 0);
    qk(scA, kA);
    if (nt > 1) kload(kB, 1);

    int t = 0;
    for (;;) {
        {   // scores in scA; next K in kB; kA free; V -> vfA
            const bool hasN = (t + 1 < nt);
            vload(vfA, t);                     // V FIRST (oldest outstanding)
            if (hasN) qk(scB, kB);             // waits only on old K buffer
            if (t + 2 < nt) kload(kA, t + 2);  // prefetch; stays in flight thru PV
            step(scA, vfA, t);                 // softmax covers V; PV partial wait
            ++t;
            if (!hasN) break;
        }
        {   // scores in scB; next K in kA; kB free; V -> vfB
            const bool hasN = (t + 1 < nt);
            vload(vfB, t);
            if (hasN) qk(scA, kA);
            if (t + 2 < nt) kload(kB, t + 2);
            step(scB, vfB, t);
            ++t;
            if (!hasN) break;
        }
    }

    // epilogue: accL[m][j] already holds per-row l at every lane; no shuffles
#pragma unroll
    for (int m = 0; m < 2; ++m) {
        float inv_j[4];
#pragma unroll
        for (int j = 0; j < 4; ++j) inv_j[j] = 1.0f / accL[m][j];
#pragma unroll
        for (int n = 0; n < 4; ++n)
#pragma unroll
            for (int j = 0; j < 4; ++j) {
                int q = q0 + m * 16 + lg * 4 + j;
                Out[(size_t)(b * SEQ + q) * DMODEL + h * DHEAD + n * 16 + l15] =
                    (__bf16)(accO[m][n][j] * inv_j[j]);
            }
    }
}

extern "C" void kernel_launch(void* const* d_in, const int* in_sizes, int n_in,
                              void* d_out, int out_size, void* d_ws, size_t ws_size,
                              hipStream_t stream) {
    const float* query = (const float*)d_in[0];
    const unsigned char* mask = (const unsigned char*)d_in[1];
    const float* w_qkv = (const float*)d_in[2];
    const float* b_qkv = (const float*)d_in[3];
    const float* w_out = (const float*)d_in[4];
    const float* b_out = (const float*)d_in[5];
    float* out = (float*)d_out;

    if (ws_size < 36200448ull) return;
    char* p = (char*)d_ws;
    int* lens = (int*)p;        p += 256;
    float* bqs = (float*)p;     p += 2304 * 4 + 256;
    __bf16* Xb = (__bf16*)p;    p += (size_t)4096 * 768 * 2;
    __bf16* Wqb = (__bf16*)p;   p += (size_t)2304 * 768 * 2;
    __bf16* Wob = (__bf16*)p;   p += (size_t)768 * 768 * 2;
    __bf16* Qd = (__bf16*)p;    p += (size_t)4096 * 768 * 2;
    __bf16* Kd = (__bf16*)p;    p += (size_t)4096 * 768 * 2;
    __bf16* Vp = (__bf16*)p;    p += (size_t)4096 * 768 * 2;
    __bf16* AOb = (__bf16*)p;   p += (size_t)4096 * 768 * 2;

    // fused convert + lens/bqs (one launch)
    prep_kernel<<<CVTBLKS + 1, 256, 0, stream>>>(query, w_qkv, w_out, Xb, Wqb, Wob,
                                                 mask, b_qkv, bqs, lens);

    // QKV projection with split outputs (Q pre-scaled; K dense per-head; V tiled-transposed)
    gemm_qkv<<<dim3(32, 18), 256, 0, stream>>>(Xb, Wqb, bqs, Qd, Kd, Vp);
    // attention: 768 blocks x 2 pipelined waves (frozen r17)
    attn_kernel<<<768, 128, 0, stream>>>(Qd, Kd, lens, Vp, AOb);
    // output projection: [4096,768] @ [768,768]^T -> f32 d_out, 64-row tiles
    gemm_out<<<dim3(64, 6), 256, 0, stream>>>(AOb, Wob, b_out, out, 4096, 768, 768);
}

// Round 19
// 123.002 us; speedup vs baseline: 1.1738x; 1.0503x over previous
//
#include <hip/hip_runtime.h>

#define BATCH 2
#define SEQ 2048
#define DMODEL 768
#define NH 12
#define DHEAD 64
#define D3 (3 * DMODEL)  // 2304

typedef float f32x4 __attribute__((ext_vector_type(4)));
typedef __bf16 bf16x8 __attribute__((ext_vector_type(8)));
typedef __bf16 bf16x4 __attribute__((ext_vector_type(4)));

#define NEG_INF (-__builtin_inff())
#define SCL 0.18033688011112042f  // (1/sqrt(64)) * log2(e), folded into W_q/b_q

__device__ __forceinline__ void g2l16(const void* g, void* l) {
    __builtin_amdgcn_global_load_lds(
        (const __attribute__((address_space(1))) void*)g,
        (__attribute__((address_space(3))) void*)l,
        16, 0, 0);
}

// one-instruction packed f32x2 -> bf16x2 (lo -> low16, hi -> high16), RNE
__device__ __forceinline__ unsigned cvtpk(float lo, float hi) {
    unsigned r;
    asm("v_cvt_pk_bf16_f32 %0, %1, %2" : "=v"(r) : "v"(lo), "v"(hi));
    return r;
}

// -------- fused prep: f32->bf16 convert for X/Wq/Wo + lens/bqs (last block) ----------
#define XQ 786432   // 2*2048*768 / 4
#define WQQ 442368  // 2304*768 / 4
#define WOQ 147456  // 768*768 / 4
#define WQROWS 147456  // float4 idx bound for w_qkv rows < 768
#define CVTBLKS 5376   // (XQ+WQQ+WOQ)/256
__global__ __launch_bounds__(256) void prep_kernel(const float* __restrict__ X,
                                                   const float* __restrict__ Wq,
                                                   const float* __restrict__ Wo,
                                                   __bf16* __restrict__ Xb,
                                                   __bf16* __restrict__ Wqb,
                                                   __bf16* __restrict__ Wob,
                                                   const unsigned char* __restrict__ mask,
                                                   const float* __restrict__ bq,
                                                   float* __restrict__ bqs,
                                                   int* __restrict__ lens) {
    if (blockIdx.x == CVTBLKS) {
        __shared__ int nz_s;
        __shared__ int cnt[2];
        if (threadIdx.x == 0) { nz_s = 0; cnt[0] = 0; cnt[1] = 0; }
        __syncthreads();
        for (int i = threadIdx.x; i < D3; i += 256)
            bqs[i] = bq[i] * (i < DMODEL ? SCL : 1.0f);
        uint4 mv = ((const uint4*)mask)[threadIdx.x];  // covers bytes [0,4096)
        if (mv.x | mv.y | mv.z | mv.w) nz_s = 1;
        __syncthreads();
        int c0 = 0, c1 = 0;
        if (nz_s) {  // bool layout
            for (int s = threadIdx.x; s < SEQ; s += 256) {
                c0 += (mask[s] != 0);
                c1 += (mask[SEQ + s] != 0);
            }
        } else {     // int32 layout
            const int* mi = (const int*)mask;
            for (int s = threadIdx.x; s < SEQ; s += 256) {
                c0 += (mi[s] != 0);
                c1 += (mi[SEQ + s] != 0);
            }
        }
        atomicAdd(&cnt[0], c0);
        atomicAdd(&cnt[1], c1);
        __syncthreads();
        if (threadIdx.x == 0) {
            lens[0] = SEQ - cnt[0];
            lens[1] = SEQ - cnt[1];
        }
        return;
    }
    int i = blockIdx.x * 256 + threadIdx.x;
    const float* s; __bf16* d; int k;
    float scl = 1.0f;
    if (i < XQ)            { s = X;  d = Xb;  k = i; }
    else if (i < XQ + WQQ) { s = Wq; d = Wqb; k = i - XQ; if (k < WQROWS) scl = SCL; }
    else                   { s = Wo; d = Wob; k = i - XQ - WQQ; }
    float4 v = ((const float4*)s)[k];
    bf16x4 o;
    o[0] = (__bf16)(v.x * scl); o[1] = (__bf16)(v.y * scl);
    o[2] = (__bf16)(v.z * scl); o[3] = (__bf16)(v.w * scl);
    ((bf16x4*)d)[k] = o;
}

// -------- QKV GEMM: split outputs: Qd natural, Kd per-head dense, Vp tiled-transposed --
// V-section epilogue packs the 4 j-values (4 consecutive keys, fixed dh) into ONE 8B
// store (cvt_pk pairs) -> 4x fewer store instructions / L2 write transactions than the
// previous 2B scatter.
__global__ __launch_bounds__(256) void gemm_qkv(const __bf16* __restrict__ A,
                                                const __bf16* __restrict__ Bw,
                                                const float* __restrict__ bias,
                                                __bf16* __restrict__ Qd,
                                                __bf16* __restrict__ Kd,
                                                __bf16* __restrict__ Vp) {
    const int K = 768;
    __shared__ __align__(16) __bf16 As[128][64];
    __shared__ __align__(16) __bf16 Bs[128][64];
    const int tid = threadIdx.x;
    const int wave = tid >> 6, lane = tid & 63;
    const int bm = blockIdx.x * 128, bn = blockIdx.y * 128;
    const int wr = (wave >> 1) * 64, wc = (wave & 1) * 64;
    const int l15 = lane & 15, lg = lane >> 4;
    const int rsub = lane >> 3;
    const int csub = (((lane & 7) ^ rsub) * 8);
    const int rswz = (l15 & 7) * 8;

    f32x4 acc[4][4] = {};

    for (int kt = 0; kt < K; kt += 64) {
#pragma unroll
        for (int it = 0; it < 4; ++it) {
            int c = it * 4 + wave;
            int row = c * 8 + rsub;
            g2l16(A + (size_t)(bm + row) * K + kt + csub, &As[0][0] + c * 512);
            g2l16(Bw + (size_t)(bn + row) * K + kt + csub, &Bs[0][0] + c * 512);
        }
        __syncthreads();
#pragma unroll
        for (int kk = 0; kk < 2; ++kk) {
            bf16x8 af[4], bfr[4];
            const int col = (kk * 32 + lg * 8) ^ rswz;
#pragma unroll
            for (int m = 0; m < 4; ++m)
                af[m] = *(const bf16x8*)(&As[0][0] + (wr + m * 16 + l15) * 64 + col);
#pragma unroll
            for (int n = 0; n < 4; ++n)
                bfr[n] = *(const bf16x8*)(&Bs[0][0] + (wc + n * 16 + l15) * 64 + col);
#pragma unroll
            for (int m = 0; m < 4; ++m)
#pragma unroll
                for (int n = 0; n < 4; ++n)
                    acc[m][n] = __builtin_amdgcn_mfma_f32_16x16x32_bf16(af[m], bfr[n], acc[m][n], 0, 0, 0);
        }
        __syncthreads();
    }

    if (bn < 768) {
        // Q section: natural layout (32B segments per store instr)
#pragma unroll
        for (int n = 0; n < 4; ++n) {
            int col = bn + wc + n * 16 + l15;
            float bv = bias[col];
#pragma unroll
            for (int m = 0; m < 4; ++m)
#pragma unroll
                for (int j = 0; j < 4; ++j) {
                    int row = bm + wr + m * 16 + lg * 4 + j;
                    Qd[(size_t)row * 768 + col] = (__bf16)(acc[m][n][j] + bv);
                }
        }
    } else if (bn < 1536) {
        // K section: per-head dense [key][dh]
#pragma unroll
        for (int n = 0; n < 4; ++n) {
            int col = bn + wc + n * 16 + l15;
            float bv = bias[col];
            int kc = col - 768;
            int hh = kc >> 6, dh = kc & 63;
#pragma unroll
            for (int m = 0; m < 4; ++m)
#pragma unroll
                for (int j = 0; j < 4; ++j) {
                    int row = bm + wr + m * 16 + lg * 4 + j;
                    int bb = row >> 11, key = row & 2047;
                    Kd[(size_t)(bb * NH + hh) * 131072 + key * 64 + dh] = (__bf16)(acc[m][n][j] + bv);
                }
        }
    } else {
        // V section: tiled-transposed [kt][dh][64key]; pack 4 consecutive keys -> 8B store
#pragma unroll
        for (int n = 0; n < 4; ++n) {
            int col = bn + wc + n * 16 + l15;
            float bv = bias[col];
            int vc = col - 1536;
            int hh = vc >> 6, dh = vc & 63;
#pragma unroll
            for (int m = 0; m < 4; ++m) {
                int row0 = bm + wr + m * 16 + lg * 4;   // multiple of 4; j spans row0..row0+3
                int bb = row0 >> 11, key = row0 & 2047; // same bb/kt for all 4 j
                uint2 o = {cvtpk(acc[m][n][0] + bv, acc[m][n][1] + bv),
                           cvtpk(acc[m][n][2] + bv, acc[m][n][3] + bv)};
                *(uint2*)&Vp[(size_t)(bb * NH + hh) * 131072 + (size_t)(key >> 6) * 4096 +
                             dh * 64 + (key & 63)] = o;
            }
        }
    }
}

// ---------------- out-projection GEMM: 64x128 tiles (384 blocks, full CU fill) --------
__global__ __launch_bounds__(256) void gemm_out(const __bf16* __restrict__ A,
                                                const __bf16* __restrict__ Bw,
                                                const float* __restrict__ bias,
                                                float* __restrict__ Cout,
                                                int M, int N, int K) {
    __shared__ __align__(16) __bf16 As[64][64];
    __shared__ __align__(16) __bf16 Bs[128][64];
    const int tid = threadIdx.x;
    const int wave = tid >> 6, lane = tid & 63;
    const int bm = blockIdx.x * 64, bn = blockIdx.y * 128;
    const int wr = (wave >> 1) * 32, wc = (wave & 1) * 64;
    const int l15 = lane & 15, lg = lane >> 4;
    const int rsub = lane >> 3;
    const int csub = (((lane & 7) ^ rsub) * 8);
    const int rswz = (l15 & 7) * 8;

    f32x4 acc[2][4] = {};

    for (int kt = 0; kt < K; kt += 64) {
#pragma unroll
        for (int it = 0; it < 2; ++it) {   // A: 8 chunks (64 rows)
            int c = it * 4 + wave;
            int row = c * 8 + rsub;
            g2l16(A + (size_t)(bm + row) * K + kt + csub, &As[0][0] + c * 512);
        }
#pragma unroll
        for (int it = 0; it < 4; ++it) {   // B: 16 chunks (128 rows)
            int c = it * 4 + wave;
            int row = c * 8 + rsub;
            g2l16(Bw + (size_t)(bn + row) * K + kt + csub, &Bs[0][0] + c * 512);
        }
        __syncthreads();
#pragma unroll
        for (int kk = 0; kk < 2; ++kk) {
            bf16x8 af[2], bfr[4];
            const int col = (kk * 32 + lg * 8) ^ rswz;
#pragma unroll
            for (int m = 0; m < 2; ++m)
                af[m] = *(const bf16x8*)(&As[0][0] + (wr + m * 16 + l15) * 64 + col);
#pragma unroll
            for (int n = 0; n < 4; ++n)
                bfr[n] = *(const bf16x8*)(&Bs[0][0] + (wc + n * 16 + l15) * 64 + col);
#pragma unroll
            for (int m = 0; m < 2; ++m)
#pragma unroll
                for (int n = 0; n < 4; ++n)
                    acc[m][n] = __builtin_amdgcn_mfma_f32_16x16x32_bf16(af[m], bfr[n], acc[m][n], 0, 0, 0);
        }
        __syncthreads();
    }

#pragma unroll
    for (int n = 0; n < 4; ++n) {
        int col = bn + wc + n * 16 + l15;
        float bv = bias[col];
#pragma unroll
        for (int m = 0; m < 2; ++m) {
#pragma unroll
            for (int j = 0; j < 4; ++j) {
                int row = bm + wr + m * 16 + lg * 4 + j;
                Cout[(size_t)row * N + col] = acc[m][n][j] + bv;
            }
        }
    }
}

// ------- flash attention: r17 (frozen) — pipeline + cvt_pk pack + l-sum via MFMA ------
__global__ __launch_bounds__(128) void attn_kernel(const __bf16* __restrict__ Qd,
                                                   const __bf16* __restrict__ Kd,
                                                   const int* __restrict__ lens,
                                                   const __bf16* __restrict__ Vp,
                                                   __bf16* __restrict__ Out) {
    const int lane = threadIdx.x & 63, wave = threadIdx.x >> 6;
    const int l15 = lane & 15, lg = lane >> 4;
    const int blk = blockIdx.x;
    const int xcd = blk & 7, idx = blk >> 3;   // idx 0..95
    const int hl = idx % 3, pd2 = idx / 3;     // pd2 0..31
    const int p = 63 - (pd2 * 2 + wave);       // heavy first; waves share bh
    const int bh = xcd * 3 + hl;
    const int b = bh / NH, h = bh % NH;
    const int len = lens[b];
    const int q0 = p * 32;

    // permuted K row for this lane: prow = (l15>>2)*8 + (l15&3)
    const int prow = ((l15 >> 2) << 3) + (l15 & 3);
    const __bf16* kbase = Kd + (size_t)bh * 131072 + prow * 64 + lg * 8;
    const __bf16* vbase = Vp + (size_t)bh * 131072 + l15 * 64 + lg * 8;

    // Q fragments (B-operand) for both subtiles
    bf16x8 qf[2][2];
    int qcap[2];
#pragma unroll
    for (int m = 0; m < 2; ++m) {
        const __bf16* qp_ = Qd + (size_t)(b * SEQ + q0 + m * 16 + l15) * DMODEL + h * DHEAD + lg * 8;
        qf[m][0] = *(const bf16x8*)qp_;
        qf[m][1] = *(const bf16x8*)(qp_ + 32);
        int myq = q0 + m * 16 + l15;
        qcap[m] = (len - 1 < myq) ? (len - 1) : myq;
    }

    int kmax = q0 + 32;
    if (len < kmax) kmax = len;
    const int nt = (kmax + 63) >> 6;

    // all-ones bf16 B-fragment for the l-sum MFMA
    const uint4 onesu = {0x3F803F80u, 0x3F803F80u, 0x3F803F80u, 0x3F803F80u};
    const bf16x8 ones = __builtin_bit_cast(bf16x8, onesu);

    f32x4 accO[2][4] = {};
    f32x4 accL[2] = {};            // accL[m][j] = running row-sum of P for row lg*4+j

    bf16x8 kA[2][4], kB[2][4];     // double-buffered K fragments
    bf16x8 vfA[2][4], vfB[2][4];   // double-buffered V fragments
    f32x4 scA[2][4], scB[2][4];    // double-buffered score tiles

    auto kload = [&](bf16x8(&kf)[2][4], int kt) {
        const int k0 = kt * 64;
#pragma unroll
        for (int n = 0; n < 4; ++n) {
            const int roff = (k0 + ((n >> 1) << 5) + ((n & 1) << 2)) * 64;
#pragma unroll
            for (int kkd = 0; kkd < 2; ++kkd)
                kf[kkd][n] = *(const bf16x8*)(kbase + roff + kkd * 32);
        }
    };

    auto vload = [&](bf16x8(&vf)[2][4], int kt) {
        const __bf16* vt = vbase + kt * 4096;
#pragma unroll
        for (int kk = 0; kk < 2; ++kk)
#pragma unroll
            for (int n = 0; n < 4; ++n)
                vf[kk][n] = *(const bf16x8*)(vt + n * 1024 + kk * 32);
    };

    auto qk = [&](f32x4(&sc)[2][4], bf16x8(&kf)[2][4]) {
        __builtin_amdgcn_s_setprio(1);
#pragma unroll
        for (int m = 0; m < 2; ++m)
#pragma unroll
            for (int n = 0; n < 4; ++n) {
                sc[m][n] = __builtin_amdgcn_mfma_f32_16x16x32_bf16(kf[0][n], qf[m][0],
                                                                   f32x4{0.f, 0.f, 0.f, 0.f}, 0, 0, 0);
                sc[m][n] = __builtin_amdgcn_mfma_f32_16x16x32_bf16(kf[1][n], qf[m][1], sc[m][n], 0, 0, 0);
            }
        __builtin_amdgcn_s_setprio(0);
    };

    auto step = [&](f32x4(&sc)[2][4], bf16x8(&vf)[2][4], int kt) {
        const int k0 = kt * 64;
        bf16x8 pa[2][2];
#pragma unroll
        for (int m = 0; m < 2; ++m) {
            const bool full = (k0 + 63 <= q0 + m * 16) && (k0 + 63 < len);
            unsigned pk[4][2];
#pragma unroll
            for (int n = 0; n < 4; ++n) {
                const int keyb = k0 + ((n >> 1) << 5) + lg * 8 + ((n & 1) << 2);
                float pv[4];
#pragma unroll
                for (int j = 0; j < 4; ++j) {
                    float e = exp2f(sc[m][n][j]);
                    if (!full) e = (keyb + j <= qcap[m]) ? e : 0.f;
                    pv[j] = e;
                }
                pk[n][0] = cvtpk(pv[0], pv[1]);
                pk[n][1] = cvtpk(pv[2], pv[3]);
            }
            uint4 u0 = {pk[0][0], pk[0][1], pk[1][0], pk[1][1]};
            uint4 u1 = {pk[2][0], pk[2][1], pk[3][0], pk[3][1]};
            pa[m][0] = __builtin_bit_cast(bf16x8, u0);
            pa[m][1] = __builtin_bit_cast(bf16x8, u1);
        }

        __builtin_amdgcn_s_setprio(1);
#pragma unroll
        for (int m = 0; m < 2; ++m) {
#pragma unroll
            for (int kk = 0; kk < 2; ++kk) {
#pragma unroll
                for (int n = 0; n < 4; ++n)
                    accO[m][n] = __builtin_amdgcn_mfma_f32_16x16x32_bf16(pa[m][kk], vf[kk][n], accO[m][n], 0, 0, 0);
                accL[m] = __builtin_amdgcn_mfma_f32_16x16x32_bf16(pa[m][kk], ones, accL[m], 0, 0, 0);
            }
        }
        __builtin_amdgcn_s_setprio(0);
    };

    // pipeline prologue: S(0) from kA; K(1) -> kB
    kload(kA, 0);
    qk(scA, kA);
    if (nt > 1) kload(kB, 1);

    int t = 0;
    for (;;) {
        {   // scores in scA; next K in kB; kA free; V -> vfA
            const bool hasN = (t + 1 < nt);
            vload(vfA, t);                     // V FIRST (oldest outstanding)
            if (hasN) qk(scB, kB);             // waits only on old K buffer
            if (t + 2 < nt) kload(kA, t + 2);  // prefetch; stays in flight thru PV
            step(scA, vfA, t);                 // softmax covers V; PV partial wait
            ++t;
            if (!hasN) break;
        }
        {   // scores in scB; next K in kA; kB free; V -> vfB
            const bool hasN = (t + 1 < nt);
            vload(vfB, t);
            if (hasN) qk(scA, kA);
            if (t + 2 < nt) kload(kB, t + 2);
            step(scB, vfB, t);
            ++t;
            if (!hasN) break;
        }
    }

    // epilogue: accL[m][j] already holds per-row l at every lane; no shuffles
#pragma unroll
    for (int m = 0; m < 2; ++m) {
        float inv_j[4];
#pragma unroll
        for (int j = 0; j < 4; ++j) inv_j[j] = 1.0f / accL[m][j];
#pragma unroll
        for (int n = 0; n < 4; ++n)
#pragma unroll
            for (int j = 0; j < 4; ++j) {
                int q = q0 + m * 16 + lg * 4 + j;
                Out[(size_t)(b * SEQ + q) * DMODEL + h * DHEAD + n * 16 + l15] =
                    (__bf16)(accO[m][n][j] * inv_j[j]);
            }
    }
}

extern "C" void kernel_launch(void* const* d_in, const int* in_sizes, int n_in,
                              void* d_out, int out_size, void* d_ws, size_t ws_size,
                              hipStream_t stream) {
    const float* query = (const float*)d_in[0];
    const unsigned char* mask = (const unsigned char*)d_in[1];
    const float* w_qkv = (const float*)d_in[2];
    const float* b_qkv = (const float*)d_in[3];
    const float* w_out = (const float*)d_in[4];
    const float* b_out = (const float*)d_in[5];
    float* out = (float*)d_out;

    if (ws_size < 36200448ull) return;
    char* p = (char*)d_ws;
    int* lens = (int*)p;        p += 256;
    float* bqs = (float*)p;     p += 2304 * 4 + 256;
    __bf16* Xb = (__bf16*)p;    p += (size_t)4096 * 768 * 2;
    __bf16* Wqb = (__bf16*)p;   p += (size_t)2304 * 768 * 2;
    __bf16* Wob = (__bf16*)p;   p += (size_t)768 * 768 * 2;
    __bf16* Qd = (__bf16*)p;    p += (size_t)4096 * 768 * 2;
    __bf16* Kd = (__bf16*)p;    p += (size_t)4096 * 768 * 2;
    __bf16* Vp = (__bf16*)p;    p += (size_t)4096 * 768 * 2;
    __bf16* AOb = (__bf16*)p;   p += (size_t)4096 * 768 * 2;

    // fused convert + lens/bqs (one launch)
    prep_kernel<<<CVTBLKS + 1, 256, 0, stream>>>(query, w_qkv, w_out, Xb, Wqb, Wob,
                                                 mask, b_qkv, bqs, lens);

    // QKV projection with split outputs (Q pre-scaled; K dense per-head; V tiled-transposed)
    gemm_qkv<<<dim3(32, 18), 256, 0, stream>>>(Xb, Wqb, bqs, Qd, Kd, Vp);
    // attention: 768 blocks x 2 pipelined waves (frozen r17)
    attn_kernel<<<768, 128, 0, stream>>>(Qd, Kd, lens, Vp, AOb);
    // output projection: [4096,768] @ [768,768]^T -> f32 d_out, 64-row tiles
    gemm_out<<<dim3(64, 6), 256, 0, stream>>>(AOb, Wob, b_out, out, 4096, 768, 768);
}